// Round 9
// baseline (7456.642 us; speedup 1.0000x reference)
//
#include <hip/hip_runtime.h>
#include <hip/hip_bf16.h>

#define NB   2048
#define NN0  111
#define NN1  56
#define NN2  28
#define FD   256
#define HD   128

// ---------------------------------------------------------------------------
// K0a: transpose weights -> wT[mat][col][k] (k-contiguous, padded to KP).
// mat order: 0=wg, 1=wsp[2], 2=wsp[1], 3=wsp[0]
// ---------------------------------------------------------------------------
__global__ __launch_bounds__(256) void k_wt(
    const float* __restrict__ wg, const float* __restrict__ wsp,
    float* __restrict__ wT, int K, int KP)
{
  int total = 4 * 128 * KP;
  for (int idx = blockIdx.x * 256 + threadIdx.x; idx < total;
       idx += gridDim.x * 256) {
    int m = idx / (128 * KP);
    int rem = idx - m * 128 * KP;
    int c = rem / KP;
    int k = rem - c * KP;
    const float* src = (m == 0) ? wg
                     : wsp + (size_t)((m == 1) ? 2 : (m == 2) ? 1 : 0) * K * HD;
    wT[idx] = (k < K) ? src[(size_t)k * HD + c] : 0.0f;
  }
}

// ---------------------------------------------------------------------------
// K0b: pad x rows to stride 112 (16B-aligned float4 rows), zeros at k=111.
// ---------------------------------------------------------------------------
__global__ __launch_bounds__(256) void k_xpad(
    const float* __restrict__ x, float* __restrict__ xp, int b0, int g)
{
  size_t total = (size_t)g * NN0 * 112;
  for (size_t idx = (size_t)blockIdx.x * 256 + threadIdx.x; idx < total;
       idx += (size_t)gridDim.x * 256) {
    int k = (int)(idx % 112);
    size_t br = idx / 112;   // local_b*111 + r
    xp[idx] = (k < NN0) ? x[((size_t)b0 * NN0 + br) * NN0 + k] : 0.0f;
  }
}

// ---------------------------------------------------------------------------
// K1: stage-1 conv. GEMM reads x (L1 broadcast) + wT (float4 stream) from
// GLOBAL; LDS only for prop buffer + masks = 31,360 B -> 2 blocks/CU.
// ---------------------------------------------------------------------------
__global__ __launch_bounds__(512, 4) void k_stage1(
    const float* __restrict__ xp, const float* __restrict__ adj,
    const float* __restrict__ wT, float* __restrict__ h1, int b0)
{
  extern __shared__ float sm[];
  float* buf  = sm;                                // 112*64 (row 111 = 0)
  unsigned* abits = (unsigned*)(buf + 7168);       // 448 u32
  float* dis0 = (float*)(abits + 448);             // 112
  float* dis1 = dis0 + 112;                        // 112

  const int tid  = threadIdx.x;
  const int lane = tid & 63;   // col
  const int wv   = tid >> 6;   // row group
  const int b    = b0 + blockIdx.x;
  const float* xb = xp + (size_t)blockIdx.x * (NN0 * 112);
  const float* ab = adj + (size_t)b * (NN0 * NN0);

  if (tid < 64) buf[111 * 64 + tid] = 0.0f;
  for (int i = wv; i < NN0; i += 8) {
    unsigned long long m0 = __ballot(ab[i * NN0 + lane] != 0.0f);
    float a1v = (64 + lane < NN0) ? ab[i * NN0 + 64 + lane] : 0.0f;
    unsigned long long m1 = __ballot(a1v != 0.0f);
    if (lane == 0) {
      abits[i * 4 + 0] = (unsigned)m0; abits[i * 4 + 1] = (unsigned)(m0 >> 32);
      abits[i * 4 + 2] = (unsigned)m1; abits[i * 4 + 3] = (unsigned)(m1 >> 32);
      int d = __popcll(m0) + __popcll(m1);
      dis0[i] = (d > 0) ? (1.0f / sqrtf((float)d)) : 0.0f;
      dis1[i] = 1.0f / sqrtf((float)(d + 1));
    }
  }
  __syncthreads();

  // 4-way ILP neighbor sum; invalid slots hit zero row 111.
  // readfirstlane returns int -> truncate to unsigned BEFORE widening.
  auto nsum = [&](int i) {
    const unsigned* rb = abits + i * 4;
    unsigned lo0 = (unsigned)__builtin_amdgcn_readfirstlane(rb[0]);
    unsigned hi0 = (unsigned)__builtin_amdgcn_readfirstlane(rb[1]);
    unsigned lo1 = (unsigned)__builtin_amdgcn_readfirstlane(rb[2]);
    unsigned hi1 = (unsigned)__builtin_amdgcn_readfirstlane(rb[3]);
    unsigned long long u0 = ((unsigned long long)hi0 << 32) | (unsigned long long)lo0;
    unsigned long long u1 = ((unsigned long long)hi1 << 32) | (unsigned long long)lo1;
    float s0 = 0.f, s1 = 0.f, s2 = 0.f, s3 = 0.f;
    while (u0 | u1) {
      int j0 = u0 ? (int)__builtin_ctzll(u0) : 111; u0 &= u0 - 1;
      int j1 = u0 ? (int)__builtin_ctzll(u0) : 111; u0 &= u0 - 1;
      int j2 = u1 ? (int)(64 + __builtin_ctzll(u1)) : 111; u1 &= u1 - 1;
      int j3 = u1 ? (int)(64 + __builtin_ctzll(u1)) : 111; u1 &= u1 - 1;
      s0 += buf[j0 * 64 + lane];
      s1 += buf[j1 * 64 + lane];
      s2 += buf[j2 * 64 + lane];
      s3 += buf[j3 * 64 + lane];
    }
    return (s0 + s1) + (s2 + s3);
  };

  float* h1b = h1 + (size_t)blockIdx.x * (NN0 * FD);

  for (int c = 0; c < 2; ++c) {
    const int c0 = c * 64;
    float aG[14], a2[14], a1[14], a0v[14];
#pragma unroll
    for (int t = 0; t < 14; ++t) { aG[t] = 0.f; a2[t] = 0.f; a1[t] = 0.f; a0v[t] = 0.f; }
    const float* tG = wT + (size_t)(0 * 128 + c0 + lane) * 112;
    const float* t2 = wT + (size_t)(1 * 128 + c0 + lane) * 112;
    const float* t1 = wT + (size_t)(2 * 128 + c0 + lane) * 112;
    const float* t0 = wT + (size_t)(3 * 128 + c0 + lane) * 112;
    for (int kq = 0; kq < 28; ++kq) {
      int k0 = kq * 4;
      float4 g4 = *(const float4*)(tG + k0);
      float4 s4 = *(const float4*)(t2 + k0);
      float4 u4 = *(const float4*)(t1 + k0);
      float4 v4 = *(const float4*)(t0 + k0);
#pragma unroll
      for (int t = 0; t < 14; ++t) {
        int r = wv + 8 * t;
        if (r < NN0) {
          float4 xq = *(const float4*)(xb + r * 112 + k0);
          aG[t]  += xq.x*g4.x + xq.y*g4.y + xq.z*g4.z + xq.w*g4.w;
          a2[t]  += xq.x*s4.x + xq.y*s4.y + xq.z*s4.z + xq.w*s4.w;
          a1[t]  += xq.x*u4.x + xq.y*u4.y + xq.z*u4.z + xq.w*u4.w;
          a0v[t] += xq.x*v4.x + xq.y*v4.y + xq.z*v4.z + xq.w*v4.w;
        }
      }
    }

    // ---- GCN ----
#pragma unroll
    for (int t = 0; t < 14; ++t) {
      int r = wv + 8 * t;
      if (r < NN0) buf[r * 64 + lane] = dis1[r] * aG[t];
    }
    __syncthreads();
    for (int t = 0; t < 14; ++t) {
      int i = wv + 8 * t;
      if (i < NN0) {
        float acc = buf[i * 64 + lane] + nsum(i);
        h1b[i * FD + c0 + lane] = fmaxf(dis1[i] * acc, 0.0f);
      }
    }
    __syncthreads();
    // ---- Cheb: buf = d0*P2 ----
#pragma unroll
    for (int t = 0; t < 14; ++t) {
      int r = wv + 8 * t;
      if (r < NN0) buf[r * 64 + lane] = dis0[r] * a2[t];
    }
    __syncthreads();
    float ur[14], cacc[14];
    for (int t = 0; t < 14; ++t) {
      int i = wv + 8 * t;
      if (i < NN0) {
        ur[t] = -dis0[i] * dis0[i] * nsum(i);
        cacc[t] = -a2[t];
      } else { ur[t] = 0.f; cacc[t] = 0.f; }
    }
    __syncthreads();
    // ---- buf = U ----
#pragma unroll
    for (int t = 0; t < 14; ++t) {
      int r = wv + 8 * t;
      if (r < NN0) buf[r * 64 + lane] = ur[t];
    }
    __syncthreads();
    for (int t = 0; t < 14; ++t) {
      int i = wv + 8 * t;
      if (i < NN0) cacc[t] -= 2.0f * dis0[i] * nsum(i);
    }
    __syncthreads();
    // ---- buf = d0*P1 ----
#pragma unroll
    for (int t = 0; t < 14; ++t) {
      int r = wv + 8 * t;
      if (r < NN0) buf[r * 64 + lane] = dis0[r] * a1[t];
    }
    __syncthreads();
    for (int t = 0; t < 14; ++t) {
      int i = wv + 8 * t;
      if (i < NN0) {
        float o = cacc[t] - dis0[i] * nsum(i) + a0v[t];
        h1b[i * FD + HD + c0 + lane] = fmaxf(o, 0.0f);
      }
    }
    __syncthreads();
  }
}

// ---------------------------------------------------------------------------
// K2: pool1 — exact f32 scores, stable top-56, gather, adjp, x1 readout
// ---------------------------------------------------------------------------
__global__ __launch_bounds__(512) void k_pool1(
    const float* __restrict__ h1, const float* __restrict__ adj,
    float* __restrict__ hp1, unsigned long long* __restrict__ adjp,
    float* __restrict__ zbuf, int b0)
{
  extern __shared__ float smemf[];
  float* hs = smemf;                               // 111*256
  unsigned* abits = (unsigned*)(hs + NN0 * FD);    // 448
  float* dinv = (float*)(abits + 448);             // 112
  float* sc = dinv + 112;                          // 112
  int* sel = (int*)(sc + 112);                     // 56

  const int tid = threadIdx.x, lane = tid & 63, wv = tid >> 6;
  const int bl = blockIdx.x;
  const int b = b0 + bl;
  const float* hb = h1 + (size_t)bl * (NN0 * FD);
  const float* ab = adj + (size_t)b * (NN0 * NN0);

  for (int q = tid; q < NN0 * 64; q += 512)
    ((float4*)hs)[q] = ((const float4*)hb)[q];
  for (int i = wv; i < NN0; i += 8) {
    unsigned long long m0 = __ballot(ab[i * NN0 + lane] != 0.0f);
    float a1v = (64 + lane < NN0) ? ab[i * NN0 + 64 + lane] : 0.0f;
    unsigned long long m1 = __ballot(a1v != 0.0f);
    if (lane == 0) {
      abits[i * 4 + 0] = (unsigned)m0; abits[i * 4 + 1] = (unsigned)(m0 >> 32);
      abits[i * 4 + 2] = (unsigned)m1; abits[i * 4 + 3] = (unsigned)(m1 >> 32);
      int d = __popcll(m0) + __popcll(m1);
      dinv[i] = (d > 0) ? (1.0f / (float)d) : 0.0f;
    }
  }
  __syncthreads();
  for (int i = wv; i < NN0; i += 8) {
    float nb0 = 0, nb1 = 0, nb2 = 0, nb3 = 0;
    const unsigned* rb = abits + i * 4;
#pragma unroll
    for (int w4 = 0; w4 < 4; ++w4) {
      unsigned u = (unsigned)__builtin_amdgcn_readfirstlane(rb[w4]);
      while (u) {
        int j = (w4 << 5) + __builtin_ctz(u); u &= u - 1;
        const float* hr = hs + j * FD + lane;
        nb0 += hr[0]; nb1 += hr[64]; nb2 += hr[128]; nb3 += hr[192];
      }
    }
    const float* hi = hs + i * FD + lane;
    float di = dinv[i];
    float s = fabsf(hi[0] - di * nb0) + fabsf(hi[64] - di * nb1)
            + fabsf(hi[128] - di * nb2) + fabsf(hi[192] - di * nb3);
    for (int off = 32; off; off >>= 1) s += __shfl_xor(s, off);
    if (lane == 0) sc[i] = s;
  }
  __syncthreads();
  if (tid < NN0) {
    float my = sc[tid];
    int cnt = 0;
    for (int j = 0; j < NN0; ++j) {
      float sj = sc[j];
      cnt += (sj > my) || (sj == my && j < tid);
    }
    if (cnt < NN1) sel[cnt] = tid;
  }
  __syncthreads();
  float* hpb = hp1 + (size_t)bl * (NN1 * FD);
  for (int r = wv; r < NN1; r += 8) {
    int i = sel[r];
    const float* hr = hs + i * FD + lane;
    float* dst = hpb + r * FD + lane;
    dst[0] = hr[0]; dst[64] = hr[64]; dst[128] = hr[128]; dst[192] = hr[192];
    int j2 = (lane < NN1) ? sel[lane] : 0;
    bool bit = (lane < NN1) && ((abits[i * 4 + (j2 >> 5)] >> (j2 & 31)) & 1);
    unsigned long long m = __ballot(bit);
    if (lane == 0) adjp[(size_t)bl * NN1 + r] = m;
  }
  __syncthreads();
  float* zb = zbuf + (size_t)bl * 8192;
  if (tid < FD) {
    float mx = -3.402823466e38f, sm2 = 0.0f;
    for (int r = 0; r < NN1; ++r) {
      float v = hs[sel[r] * FD + tid];
      mx = fmaxf(mx, v); sm2 += v;
    }
    zb[7168 + tid] = mx;
    zb[7424 + tid] = sm2 / 56.0f;
  }
}

// ---------------------------------------------------------------------------
// K3: stage-2 conv. GEMM reads hp1 + wT2 from GLOBAL; LDS = 15,552 B.
// ---------------------------------------------------------------------------
__global__ __launch_bounds__(512, 4) void k_stage2(
    const float* __restrict__ hp1, const unsigned long long* __restrict__ adjp,
    const float* __restrict__ wT, float* __restrict__ h2)
{
  extern __shared__ float sm[];
  float* buf  = sm;                                // 57*64 (row 56 = 0)
  unsigned long long* rowm = (unsigned long long*)(buf + 57 * 64); // 56 u64
  float* dis0 = (float*)(rowm + 56);               // 64
  float* dis1 = dis0 + 64;                         // 64

  const int tid = threadIdx.x, lane = tid & 63, wv = tid >> 6;
  const int bl = blockIdx.x;
  const float* hb = hp1 + (size_t)bl * (NN1 * FD);
  if (tid < 64) buf[56 * 64 + tid] = 0.0f;
  if (tid < NN1) {
    unsigned long long m = adjp[(size_t)bl * NN1 + tid];
    rowm[tid] = m;
    int d = __popcll(m);
    dis0[tid] = (d > 0) ? (1.0f / sqrtf((float)d)) : 0.0f;
    dis1[tid] = 1.0f / sqrtf((float)(d + 1));
  }
  __syncthreads();

  auto nsum = [&](int i) {
    unsigned long long m = rowm[i];
    unsigned lo = (unsigned)__builtin_amdgcn_readfirstlane((unsigned)m);
    unsigned hi = (unsigned)__builtin_amdgcn_readfirstlane((unsigned)(m >> 32));
    unsigned long long u = ((unsigned long long)hi << 32) | (unsigned long long)lo;
    float s0 = 0.f, s1 = 0.f, s2 = 0.f, s3 = 0.f;
    while (u) {
      int j0 = (int)__builtin_ctzll(u); u &= u - 1;
      int j1 = u ? (int)__builtin_ctzll(u) : 56; u &= u - 1;
      int j2 = u ? (int)__builtin_ctzll(u) : 56; u &= u - 1;
      int j3 = u ? (int)__builtin_ctzll(u) : 56; u &= u - 1;
      s0 += buf[j0 * 64 + lane];
      s1 += buf[j1 * 64 + lane];
      s2 += buf[j2 * 64 + lane];
      s3 += buf[j3 * 64 + lane];
    }
    return (s0 + s1) + (s2 + s3);
  };

  float* h2b = h2 + (size_t)bl * (NN1 * FD);

  for (int c = 0; c < 2; ++c) {
    const int c0 = c * 64;
    float aG[7], a2[7], a1[7], a0v[7];
#pragma unroll
    for (int t = 0; t < 7; ++t) { aG[t] = 0.f; a2[t] = 0.f; a1[t] = 0.f; a0v[t] = 0.f; }
    const float* tG = wT + (size_t)(0 * 128 + c0 + lane) * 256;
    const float* t2 = wT + (size_t)(1 * 128 + c0 + lane) * 256;
    const float* t1 = wT + (size_t)(2 * 128 + c0 + lane) * 256;
    const float* t0 = wT + (size_t)(3 * 128 + c0 + lane) * 256;
    for (int kq = 0; kq < 64; ++kq) {
      int k0 = kq * 4;
      float4 g4 = *(const float4*)(tG + k0);
      float4 s4 = *(const float4*)(t2 + k0);
      float4 u4 = *(const float4*)(t1 + k0);
      float4 v4 = *(const float4*)(t0 + k0);
#pragma unroll
      for (int t = 0; t < 7; ++t) {
        int r = wv + 8 * t;
        float4 xq = *(const float4*)(hb + r * FD + k0);
        aG[t]  += xq.x*g4.x + xq.y*g4.y + xq.z*g4.z + xq.w*g4.w;
        a2[t]  += xq.x*s4.x + xq.y*s4.y + xq.z*s4.z + xq.w*s4.w;
        a1[t]  += xq.x*u4.x + xq.y*u4.y + xq.z*u4.z + xq.w*u4.w;
        a0v[t] += xq.x*v4.x + xq.y*v4.y + xq.z*v4.z + xq.w*v4.w;
      }
    }
    // GCN
#pragma unroll
    for (int t = 0; t < 7; ++t) buf[(wv + 8*t) * 64 + lane] = dis1[wv + 8*t] * aG[t];
    __syncthreads();
#pragma unroll
    for (int t = 0; t < 7; ++t) {
      int i = wv + 8 * t;
      float acc = buf[i * 64 + lane] + nsum(i);
      h2b[i * FD + c0 + lane] = fmaxf(dis1[i] * acc, 0.0f);
    }
    __syncthreads();
    // Cheb
#pragma unroll
    for (int t = 0; t < 7; ++t) buf[(wv + 8*t) * 64 + lane] = dis0[wv + 8*t] * a2[t];
    __syncthreads();
    float ur[7], cacc[7];
#pragma unroll
    for (int t = 0; t < 7; ++t) {
      int i = wv + 8 * t;
      ur[t] = -dis0[i] * dis0[i] * nsum(i);
      cacc[t] = -a2[t];
    }
    __syncthreads();
#pragma unroll
    for (int t = 0; t < 7; ++t) buf[(wv + 8*t) * 64 + lane] = ur[t];
    __syncthreads();
#pragma unroll
    for (int t = 0; t < 7; ++t) {
      int i = wv + 8 * t;
      cacc[t] -= 2.0f * dis0[i] * nsum(i);
    }
    __syncthreads();
#pragma unroll
    for (int t = 0; t < 7; ++t) buf[(wv + 8*t) * 64 + lane] = dis0[wv + 8*t] * a1[t];
    __syncthreads();
#pragma unroll
    for (int t = 0; t < 7; ++t) {
      int i = wv + 8 * t;
      float o = cacc[t] - dis0[i] * nsum(i) + a0v[t];
      h2b[i * FD + HD + c0 + lane] = fmaxf(o, 0.0f);
    }
    __syncthreads();
  }
}

// ---------------------------------------------------------------------------
// K4: pool2 + readout; flat h -> zbuf[0..7167], x2 -> zbuf[7680..]
// ---------------------------------------------------------------------------
__global__ __launch_bounds__(256) void k_pool2(
    const float* __restrict__ h2, const unsigned long long* __restrict__ adjp,
    float* __restrict__ zbuf)
{
  extern __shared__ float smemf[];
  float* hs = smemf;                                        // 56*256
  unsigned long long* rowm = (unsigned long long*)(hs + NN1 * FD);
  float* dinv = (float*)(rowm + 56);
  float* sc = dinv + 64;
  int* sel = (int*)(sc + 64);

  const int tid = threadIdx.x, lane = tid & 63, wv = tid >> 6;
  const int bl = blockIdx.x;
  const float* hb = h2 + (size_t)bl * (NN1 * FD);
  for (int q = tid; q < NN1 * 64; q += 256)
    ((float4*)hs)[q] = ((const float4*)hb)[q];
  if (tid < NN1) {
    unsigned long long m = adjp[(size_t)bl * NN1 + tid];
    rowm[tid] = m;
    int d = __popcll(m);
    dinv[tid] = (d > 0) ? (1.0f / (float)d) : 0.0f;
  }
  __syncthreads();
  for (int i = wv; i < NN1; i += 4) {
    float nb0 = 0, nb1 = 0, nb2 = 0, nb3 = 0;
    unsigned long long m = rowm[i];
    unsigned ulo = (unsigned)__builtin_amdgcn_readfirstlane((unsigned)m);
    unsigned uhi = (unsigned)__builtin_amdgcn_readfirstlane((unsigned)(m >> 32));
    while (ulo) {
      int j = __builtin_ctz(ulo); ulo &= ulo - 1;
      const float* hr = hs + j * FD + lane;
      nb0 += hr[0]; nb1 += hr[64]; nb2 += hr[128]; nb3 += hr[192];
    }
    while (uhi) {
      int j = 32 + __builtin_ctz(uhi); uhi &= uhi - 1;
      const float* hr = hs + j * FD + lane;
      nb0 += hr[0]; nb1 += hr[64]; nb2 += hr[128]; nb3 += hr[192];
    }
    const float* hi = hs + i * FD + lane;
    float di = dinv[i];
    float s = fabsf(hi[0] - di * nb0) + fabsf(hi[64] - di * nb1)
            + fabsf(hi[128] - di * nb2) + fabsf(hi[192] - di * nb3);
    for (int off = 32; off; off >>= 1) s += __shfl_xor(s, off);
    if (lane == 0) sc[i] = s;
  }
  __syncthreads();
  if (tid < NN1) {
    float my = sc[tid];
    int cnt = 0;
    for (int j = 0; j < NN1; ++j) {
      float sj = sc[j];
      cnt += (sj > my) || (sj == my && j < tid);
    }
    if (cnt < NN2) sel[cnt] = tid;
  }
  __syncthreads();
  float* zb = zbuf + (size_t)bl * 8192;
  for (int r = wv; r < NN2; r += 4) {
    const float* hr = hs + sel[r] * FD + lane;
    float* dst = zb + r * FD + lane;
    dst[0] = hr[0]; dst[64] = hr[64]; dst[128] = hr[128]; dst[192] = hr[192];
  }
  {
    float mx = -3.402823466e38f, sm2 = 0.0f;
    for (int r = 0; r < NN2; ++r) {
      float v = hs[sel[r] * FD + tid];
      mx = fmaxf(mx, v); sm2 += v;
    }
    zb[7680 + tid] = mx;
    zb[7936 + tid] = sm2 / 28.0f;
  }
}

// ---------------------------------------------------------------------------
// K5: fused lin1. Block = 8 graphs x full K x all 256 cols. 512 thr.
// ---------------------------------------------------------------------------
__global__ __launch_bounds__(512) void k_lin1f(
    const float* __restrict__ zbuf, const float* __restrict__ w,
    const float* __restrict__ bias, float* __restrict__ fbuf)
{
  __shared__ float smem[8576];           // wt: 32*260=8320 | zt: 32*8=256
  float* wt = smem;
  float* zt = smem + 8320;

  const int tid = threadIdx.x;
  const int col = tid & 63;
  const int ksub = tid >> 6;             // 0..7
  const int g0 = blockIdx.x * 8;
  const int gz = tid >> 5, kz = tid & 31;  // z staging (tid<256)

  float acc[8][4];
#pragma unroll
  for (int g = 0; g < 8; ++g)
#pragma unroll
    for (int c = 0; c < 4; ++c) acc[g][c] = 0.f;

  const float* wbase = w + (size_t)ksub * 256 + col * 4;
  const float* zbase = zbuf + (size_t)(g0 + gz) * 8192 + kz;

  float4 wr4[4]; float zr1 = 0.f;
#pragma unroll
  for (int q = 0; q < 4; ++q)
    wr4[q] = *(const float4*)(wbase + (size_t)(8 * q) * 256);
  if (tid < 256) zr1 = zbase[0];
#pragma unroll
  for (int q = 0; q < 4; ++q)
    *(float4*)&wt[(ksub + 8 * q) * 260 + col * 4] = wr4[q];
  if (tid < 256) zt[kz * 8 + gz] = zr1;
  __syncthreads();

  for (int it = 0; it < 256; ++it) {
    if (it + 1 < 256) {
      const float* wn = wbase + (size_t)(it + 1) * 32 * 256;
#pragma unroll
      for (int q = 0; q < 4; ++q)
        wr4[q] = *(const float4*)(wn + (size_t)(8 * q) * 256);
      if (tid < 256) zr1 = zbase[(it + 1) * 32];
    }
#pragma unroll
    for (int kk = 0; kk < 4; ++kk) {
      int k = ksub * 4 + kk;
      float4 za = *(const float4*)&zt[k * 8];
      float4 zb = *(const float4*)&zt[k * 8 + 4];
      float4 wv = *(const float4*)&wt[k * 260 + col * 4];
      acc[0][0] += za.x * wv.x; acc[0][1] += za.x * wv.y; acc[0][2] += za.x * wv.z; acc[0][3] += za.x * wv.w;
      acc[1][0] += za.y * wv.x; acc[1][1] += za.y * wv.y; acc[1][2] += za.y * wv.z; acc[1][3] += za.y * wv.w;
      acc[2][0] += za.z * wv.x; acc[2][1] += za.z * wv.y; acc[2][2] += za.z * wv.z; acc[2][3] += za.z * wv.w;
      acc[3][0] += za.w * wv.x; acc[3][1] += za.w * wv.y; acc[3][2] += za.w * wv.z; acc[3][3] += za.w * wv.w;
      acc[4][0] += zb.x * wv.x; acc[4][1] += zb.x * wv.y; acc[4][2] += zb.x * wv.z; acc[4][3] += zb.x * wv.w;
      acc[5][0] += zb.y * wv.x; acc[5][1] += zb.y * wv.y; acc[5][2] += zb.y * wv.z; acc[5][3] += zb.y * wv.w;
      acc[6][0] += zb.z * wv.x; acc[6][1] += zb.z * wv.y; acc[6][2] += zb.z * wv.z; acc[6][3] += zb.z * wv.w;
      acc[7][0] += zb.w * wv.x; acc[7][1] += zb.w * wv.y; acc[7][2] += zb.w * wv.z; acc[7][3] += zb.w * wv.w;
    }
    __syncthreads();
    if (it + 1 < 256) {
#pragma unroll
      for (int q = 0; q < 4; ++q)
        *(float4*)&wt[(ksub + 8 * q) * 260 + col * 4] = wr4[q];
      if (tid < 256) zt[kz * 8 + gz] = zr1;
      __syncthreads();
    }
  }

  // reduce 8 ksub partials (tree via LDS)
  float* red = smem;
  for (int half = 4; half >= 1; half >>= 1) {
    if (ksub >= half && ksub < 2 * half) {
      float* dst = red + ((ksub - half) * 64 + col) * 33;
#pragma unroll
      for (int g = 0; g < 8; ++g)
#pragma unroll
        for (int c = 0; c < 4; ++c) dst[g * 4 + c] = acc[g][c];
    }
    __syncthreads();
    if (ksub < half) {
      const float* src = red + (ksub * 64 + col) * 33;
#pragma unroll
      for (int g = 0; g < 8; ++g)
#pragma unroll
        for (int c = 0; c < 4; ++c) acc[g][c] += src[g * 4 + c];
    }
    __syncthreads();
  }
  if (ksub == 0) {
    float4 bv = *(const float4*)(bias + col * 4);
#pragma unroll
    for (int g = 0; g < 8; ++g) {
      float4 o;
      o.x = fmaxf(acc[g][0] + bv.x, 0.f);
      o.y = fmaxf(acc[g][1] + bv.y, 0.f);
      o.z = fmaxf(acc[g][2] + bv.z, 0.f);
      o.w = fmaxf(acc[g][3] + bv.w, 0.f);
      *(float4*)&fbuf[(size_t)(g0 + g) * 256 + col * 4] = o;
    }
  }
}

// ---------------------------------------------------------------------------
// K6: features = relu(f @ lin2_w + b2); x_lo = softmax(features)
// ---------------------------------------------------------------------------
__global__ __launch_bounds__(128) void k_head(
    const float* __restrict__ fbuf, const float* __restrict__ w2,
    const float* __restrict__ b2, float* __restrict__ out, int b0)
{
  __shared__ __align__(16) float fs[256];
  __shared__ float red[2];
  const int tid = threadIdx.x, lane = tid & 63, wv = tid >> 6;
  const int bl = blockIdx.x, b = b0 + bl;
  for (int i = tid; i < 256; i += 128) fs[i] = fbuf[(size_t)bl * 256 + i];
  __syncthreads();
  float acc = b2[tid];
  for (int k = 0; k < 256; k += 4) {
    float4 fq = *(const float4*)(fs + k);
    acc += fq.x * w2[(k + 0) * 128 + tid] + fq.y * w2[(k + 1) * 128 + tid]
         + fq.z * w2[(k + 2) * 128 + tid] + fq.w * w2[(k + 3) * 128 + tid];
  }
  float feat = fmaxf(acc, 0.0f);
  out[(size_t)(NB * 128) + (size_t)b * 128 + tid] = feat;
  float m = feat;
  for (int off = 32; off; off >>= 1) m = fmaxf(m, __shfl_xor(m, off));
  if (lane == 0) red[wv] = m;
  __syncthreads();
  m = fmaxf(red[0], red[1]);
  float e = expf(feat - m);
  float s = e;
  for (int off = 32; off; off >>= 1) s += __shfl_xor(s, off);
  __syncthreads();
  if (lane == 0) red[wv] = s;
  __syncthreads();
  s = red[0] + red[1];
  out[(size_t)b * 128 + tid] = e / s;
}

// ---------------------------------------------------------------------------
extern "C" void kernel_launch(void* const* d_in, const int* in_sizes, int n_in,
                              void* d_out, int out_size, void* d_ws, size_t ws_size,
                              hipStream_t stream) {
  const float* x    = (const float*)d_in[0];
  const float* adj  = (const float*)d_in[1];
  const float* wg1  = (const float*)d_in[2];
  const float* wsp1 = (const float*)d_in[3];
  const float* wg2  = (const float*)d_in[4];
  const float* wsp2 = (const float*)d_in[5];
  const float* l1w  = (const float*)d_in[6];
  const float* l1b  = (const float*)d_in[7];
  const float* l2w  = (const float*)d_in[8];
  const float* l2b  = (const float*)d_in[9];
  float* out = (float*)d_out;

  auto al = [](size_t v) { return (v + 255) & ~(size_t)255; };
  size_t owt1, owt2, oxp, oh1, ohp1, oadjp, oz, of;
  auto plan = [&](int g) -> size_t {
    size_t o = 0;
    owt1 = o;  o += al((size_t)4 * 128 * 112 * 4);
    owt2 = o;  o += al((size_t)4 * 128 * 256 * 4);
    oxp = o;   o += al((size_t)g * NN0 * 112 * 4);
    oh1 = o;   o += al((size_t)g * NN0 * FD * 4);   // h1 (h2 overlay)
    ohp1 = o;  o += al((size_t)g * NN1 * FD * 4);
    oadjp = o; o += al((size_t)g * NN1 * 8);
    oz = o;    o += al((size_t)g * 8192 * 4);
    of = o;    o += al((size_t)g * FD * 4);
    return o;
  };
  int G = 2048;
  while (G > 64 && plan(G) > ws_size) G >>= 1;
  if (plan(G) > ws_size) return;

  char* wsb = (char*)d_ws;
  float* wT1 = (float*)(wsb + owt1);
  float* wT2 = (float*)(wsb + owt2);
  float* xp  = (float*)(wsb + oxp);
  float* h1  = (float*)(wsb + oh1);
  float* hp1 = (float*)(wsb + ohp1);
  unsigned long long* adjp = (unsigned long long*)(wsb + oadjp);
  float* zbuf = (float*)(wsb + oz);
  float* fbuf = (float*)(wsb + of);

  const size_t LDS1 = (size_t)(7168 + 448 + 112 + 112) * 4;           // 31,360
  const size_t LDS2 = (size_t)(NN0*FD + 448 + 112 + 112 + 56) * 4;    // 116,576
  const size_t LDS3 = (size_t)(57*64 + 112 + 64 + 64) * 4;            // 15,552
  const size_t LDS4 = (size_t)(NN1*FD + 112 + 64 + 64 + 32) * 4;      // 58,432

  k_wt<<<224, 256, 0, stream>>>(wg1, wsp1, wT1, NN0, 112);
  k_wt<<<512, 256, 0, stream>>>(wg2, wsp2, wT2, FD, 256);

  for (int b0 = 0; b0 < NB; b0 += G) {
    k_xpad<<<2048, 256, 0, stream>>>(x, xp, b0, G);
    k_stage1<<<G, 512, LDS1, stream>>>(xp, adj, wT1, h1, b0);
    k_pool1<<<G, 512, LDS2, stream>>>(h1, adj, hp1, adjp, zbuf, b0);
    k_stage2<<<G, 512, LDS3, stream>>>(hp1, adjp, wT2, h1);
    k_pool2<<<G, 256, LDS4, stream>>>(h1, adjp, zbuf);
    k_lin1f<<<G / 8, 512, 0, stream>>>(zbuf, l1w, l1b, fbuf);
    k_head<<<G, 128, 0, stream>>>(fbuf, l2w, l2b, out, b0);
  }
}

// Round 10
// 4361.817 us; speedup vs baseline: 1.7095x; 1.7095x over previous
//
#include <hip/hip_runtime.h>
#include <hip/hip_bf16.h>

#define NB   2048
#define NN0  111
#define NN1  56
#define NN2  28
#define FD   256
#define HD   128

// ---------------------------------------------------------------------------
// K1: stage-1 conv. One block/graph, 512 thr. Lane owns cols (2*lane, 2*lane+1).
// GEMM: 2 sweeps (s=0/1), 4 matrices each, xs b128 broadcast.
// Props: wide buf[112][128], float2 (b64) reads/writes, 4 phases.
// LDS = 109,760 B.
// ---------------------------------------------------------------------------
__global__ __launch_bounds__(512) void k_stage1(
    const float* __restrict__ x, const float* __restrict__ adj,
    const float* __restrict__ wg, const float* __restrict__ wsp,
    float* __restrict__ h1, int b0)
{
  extern __shared__ float sm[];
  float* xs   = sm;                                // 111*112 = 12432
  float* bufw = xs + 12432;                        // 112*128 = 14336 (row 111 = 0)
  unsigned* abits = (unsigned*)(bufw + 14336);     // 448 u32
  float* dis0 = (float*)(abits + 448);             // 112
  float* dis1 = dis0 + 112;                        // 112

  const int tid  = threadIdx.x;
  const int lane = tid & 63;
  const int wv   = tid >> 6;
  const int b    = b0 + blockIdx.x;
  const float* xb = x   + (size_t)b * (NN0 * NN0);
  const float* ab = adj + (size_t)b * (NN0 * NN0);

  for (int idx = tid; idx < NN0 * NN0; idx += 512) {
    int i = idx / NN0, k = idx - i * NN0;
    xs[i * 112 + k] = xb[idx];
  }
  if (tid < 128) bufw[111 * 128 + tid] = 0.0f;
  for (int i = wv; i < NN0; i += 8) {
    unsigned long long m0 = __ballot(ab[i * NN0 + lane] != 0.0f);
    float a1v = (64 + lane < NN0) ? ab[i * NN0 + 64 + lane] : 0.0f;
    unsigned long long m1 = __ballot(a1v != 0.0f);
    if (lane == 0) {
      abits[i * 4 + 0] = (unsigned)m0; abits[i * 4 + 1] = (unsigned)(m0 >> 32);
      abits[i * 4 + 2] = (unsigned)m1; abits[i * 4 + 3] = (unsigned)(m1 >> 32);
      int d = __popcll(m0) + __popcll(m1);
      dis0[i] = (d > 0) ? (1.0f / sqrtf((float)d)) : 0.0f;
      dis1[i] = 1.0f / sqrtf((float)(d + 1));
    }
  }
  __syncthreads();

  // float2 neighbor sum over bufw; 4-way ILP; invalid slots hit zero row 111.
  // readfirstlane returns int -> truncate to unsigned BEFORE widening.
  auto nsum2 = [&](int i) {
    const unsigned* rb = abits + i * 4;
    unsigned lo0 = (unsigned)__builtin_amdgcn_readfirstlane(rb[0]);
    unsigned hi0 = (unsigned)__builtin_amdgcn_readfirstlane(rb[1]);
    unsigned lo1 = (unsigned)__builtin_amdgcn_readfirstlane(rb[2]);
    unsigned hi1 = (unsigned)__builtin_amdgcn_readfirstlane(rb[3]);
    unsigned long long u0 = ((unsigned long long)hi0 << 32) | (unsigned long long)lo0;
    unsigned long long u1 = ((unsigned long long)hi1 << 32) | (unsigned long long)lo1;
    float2 s0 = {0,0}, s1 = {0,0}, s2 = {0,0}, s3 = {0,0};
    while (u0 | u1) {
      int j0 = u0 ? (int)__builtin_ctzll(u0) : 111; u0 &= u0 - 1;
      int j1 = u0 ? (int)__builtin_ctzll(u0) : 111; u0 &= u0 - 1;
      int j2 = u1 ? (int)(64 + __builtin_ctzll(u1)) : 111; u1 &= u1 - 1;
      int j3 = u1 ? (int)(64 + __builtin_ctzll(u1)) : 111; u1 &= u1 - 1;
      float2 p0 = *(const float2*)&bufw[j0 * 128 + 2 * lane];
      float2 p1 = *(const float2*)&bufw[j1 * 128 + 2 * lane];
      float2 p2 = *(const float2*)&bufw[j2 * 128 + 2 * lane];
      float2 p3 = *(const float2*)&bufw[j3 * 128 + 2 * lane];
      s0.x += p0.x; s0.y += p0.y; s1.x += p1.x; s1.y += p1.y;
      s2.x += p2.x; s2.y += p2.y; s3.x += p3.x; s3.y += p3.y;
    }
    return make_float2((s0.x + s1.x) + (s2.x + s3.x),
                       (s0.y + s1.y) + (s2.y + s3.y));
  };

  float* h1b = h1 + (size_t)blockIdx.x * (NN0 * FD);

  // ---- GEMM: sweep s computes col 2*lane+s for all 4 matrices ----
  float a2r[2][14], a1r[2][14], a0r[2][14];
#pragma unroll
  for (int s = 0; s < 2; ++s) {
    float aG[14], q2[14], q1[14], q0[14];
#pragma unroll
    for (int t = 0; t < 14; ++t) { aG[t] = 0.f; q2[t] = 0.f; q1[t] = 0.f; q0[t] = 0.f; }
    const float* pG = wg  + 2 * lane + s;
    const float* p2 = wsp + 2 * (NN0 * HD) + 2 * lane + s;
    const float* p1 = wsp + 1 * (NN0 * HD) + 2 * lane + s;
    const float* p0 = wsp + 2 * lane + s;
    for (int kq = 0; kq < 27; ++kq) {
      int k0 = kq * 4;
      float g0 = pG[(k0+0)*HD], g1 = pG[(k0+1)*HD], g2 = pG[(k0+2)*HD], g3 = pG[(k0+3)*HD];
      float s0 = p2[(k0+0)*HD], s1 = p2[(k0+1)*HD], s2 = p2[(k0+2)*HD], s3 = p2[(k0+3)*HD];
      float u0 = p1[(k0+0)*HD], u1 = p1[(k0+1)*HD], u2 = p1[(k0+2)*HD], u3 = p1[(k0+3)*HD];
      float v0 = p0[(k0+0)*HD], v1 = p0[(k0+1)*HD], v2 = p0[(k0+2)*HD], v3 = p0[(k0+3)*HD];
#pragma unroll
      for (int t = 0; t < 14; ++t) {
        int r = wv + 8 * t;
        if (r < NN0) {
          float4 xq = *(const float4*)(xs + r * 112 + k0);
          aG[t] += xq.x*g0 + xq.y*g1 + xq.z*g2 + xq.w*g3;
          q2[t] += xq.x*s0 + xq.y*s1 + xq.z*s2 + xq.w*s3;
          q1[t] += xq.x*u0 + xq.y*u1 + xq.z*u2 + xq.w*u3;
          q0[t] += xq.x*v0 + xq.y*v1 + xq.z*v2 + xq.w*v3;
        }
      }
    }
#pragma unroll
    for (int k = 108; k < 111; ++k) {
      float gv = pG[k*HD], sv = p2[k*HD], uv = p1[k*HD], vv = p0[k*HD];
#pragma unroll
      for (int t = 0; t < 14; ++t) {
        int r = wv + 8 * t;
        if (r < NN0) {
          float xv = xs[r * 112 + k];
          aG[t] += xv * gv; q2[t] += xv * sv; q1[t] += xv * uv; q0[t] += xv * vv;
        }
      }
    }
#pragma unroll
    for (int t = 0; t < 14; ++t) {
      int r = wv + 8 * t;
      if (r < NN0) bufw[r * 128 + 2 * lane + s] = dis1[r] * aG[t];
      a2r[s][t] = q2[t]; a1r[s][t] = q1[t]; a0r[s][t] = q0[t];
    }
  }
  __syncthreads();

  // ---- GCN prop (wide) ----
  for (int t = 0; t < 14; ++t) {
    int i = wv + 8 * t;
    if (i < NN0) {
      float2 self = *(const float2*)&bufw[i * 128 + 2 * lane];
      float2 ns = nsum2(i);
      float d1 = dis1[i];
      float2 o = make_float2(fmaxf(d1 * (self.x + ns.x), 0.f),
                             fmaxf(d1 * (self.y + ns.y), 0.f));
      *(float2*)&h1b[i * FD + 2 * lane] = o;
    }
  }
  __syncthreads();
  // ---- bufw = d0 * P2 ----
#pragma unroll
  for (int t = 0; t < 14; ++t) {
    int r = wv + 8 * t;
    if (r < NN0) {
      float d0r = dis0[r];
      *(float2*)&bufw[r * 128 + 2 * lane] = make_float2(d0r * a2r[0][t], d0r * a2r[1][t]);
    }
  }
  __syncthreads();
  // ---- U phase ----
  float2 ur[14], cacc[14];
  for (int t = 0; t < 14; ++t) {
    int i = wv + 8 * t;
    if (i < NN0) {
      float2 ns = nsum2(i);
      float sc0 = -dis0[i] * dis0[i];
      ur[t] = make_float2(sc0 * ns.x, sc0 * ns.y);
      cacc[t] = make_float2(-a2r[0][t], -a2r[1][t]);
    } else { ur[t] = make_float2(0.f, 0.f); cacc[t] = make_float2(0.f, 0.f); }
  }
  __syncthreads();
#pragma unroll
  for (int t = 0; t < 14; ++t) {
    int r = wv + 8 * t;
    if (r < NN0) *(float2*)&bufw[r * 128 + 2 * lane] = ur[t];
  }
  __syncthreads();
  // ---- V phase ----
  for (int t = 0; t < 14; ++t) {
    int i = wv + 8 * t;
    if (i < NN0) {
      float2 ns = nsum2(i);
      float d0i = dis0[i];
      cacc[t].x -= 2.0f * d0i * ns.x;
      cacc[t].y -= 2.0f * d0i * ns.y;
    }
  }
  __syncthreads();
  // ---- bufw = d0 * P1 ----
#pragma unroll
  for (int t = 0; t < 14; ++t) {
    int r = wv + 8 * t;
    if (r < NN0) {
      float d0r = dis0[r];
      *(float2*)&bufw[r * 128 + 2 * lane] = make_float2(d0r * a1r[0][t], d0r * a1r[1][t]);
    }
  }
  __syncthreads();
  // ---- T1 + output ----
  for (int t = 0; t < 14; ++t) {
    int i = wv + 8 * t;
    if (i < NN0) {
      float2 ns = nsum2(i);
      float d0i = dis0[i];
      float2 o = make_float2(fmaxf(cacc[t].x - d0i * ns.x + a0r[0][t], 0.f),
                             fmaxf(cacc[t].y - d0i * ns.y + a0r[1][t], 0.f));
      *(float2*)&h1b[i * FD + HD + 2 * lane] = o;
    }
  }
}

// ---------------------------------------------------------------------------
// K2: pool1 — exact f32 scores, stable top-56, gather, adjp, x1 readout
// ---------------------------------------------------------------------------
__global__ __launch_bounds__(512) void k_pool1(
    const float* __restrict__ h1, const float* __restrict__ adj,
    float* __restrict__ hp1, unsigned long long* __restrict__ adjp,
    float* __restrict__ zbuf, int b0)
{
  extern __shared__ float smemf[];
  float* hs = smemf;                               // 111*256
  unsigned* abits = (unsigned*)(hs + NN0 * FD);    // 448
  float* dinv = (float*)(abits + 448);             // 112
  float* sc = dinv + 112;                          // 112
  int* sel = (int*)(sc + 112);                     // 56

  const int tid = threadIdx.x, lane = tid & 63, wv = tid >> 6;
  const int bl = blockIdx.x;
  const int b = b0 + bl;
  const float* hb = h1 + (size_t)bl * (NN0 * FD);
  const float* ab = adj + (size_t)b * (NN0 * NN0);

  for (int q = tid; q < NN0 * 64; q += 512)
    ((float4*)hs)[q] = ((const float4*)hb)[q];
  for (int i = wv; i < NN0; i += 8) {
    unsigned long long m0 = __ballot(ab[i * NN0 + lane] != 0.0f);
    float a1v = (64 + lane < NN0) ? ab[i * NN0 + 64 + lane] : 0.0f;
    unsigned long long m1 = __ballot(a1v != 0.0f);
    if (lane == 0) {
      abits[i * 4 + 0] = (unsigned)m0; abits[i * 4 + 1] = (unsigned)(m0 >> 32);
      abits[i * 4 + 2] = (unsigned)m1; abits[i * 4 + 3] = (unsigned)(m1 >> 32);
      int d = __popcll(m0) + __popcll(m1);
      dinv[i] = (d > 0) ? (1.0f / (float)d) : 0.0f;
    }
  }
  __syncthreads();
  for (int i = wv; i < NN0; i += 8) {
    float nb0 = 0, nb1 = 0, nb2 = 0, nb3 = 0;
    const unsigned* rb = abits + i * 4;
#pragma unroll
    for (int w4 = 0; w4 < 4; ++w4) {
      unsigned u = (unsigned)__builtin_amdgcn_readfirstlane(rb[w4]);
      while (u) {
        int j = (w4 << 5) + __builtin_ctz(u); u &= u - 1;
        const float* hr = hs + j * FD + lane;
        nb0 += hr[0]; nb1 += hr[64]; nb2 += hr[128]; nb3 += hr[192];
      }
    }
    const float* hi = hs + i * FD + lane;
    float di = dinv[i];
    float s = fabsf(hi[0] - di * nb0) + fabsf(hi[64] - di * nb1)
            + fabsf(hi[128] - di * nb2) + fabsf(hi[192] - di * nb3);
    for (int off = 32; off; off >>= 1) s += __shfl_xor(s, off);
    if (lane == 0) sc[i] = s;
  }
  __syncthreads();
  if (tid < NN0) {
    float my = sc[tid];
    int cnt = 0;
    for (int j = 0; j < NN0; ++j) {
      float sj = sc[j];
      cnt += (sj > my) || (sj == my && j < tid);
    }
    if (cnt < NN1) sel[cnt] = tid;
  }
  __syncthreads();
  float* hpb = hp1 + (size_t)bl * (NN1 * FD);
  for (int r = wv; r < NN1; r += 8) {
    int i = sel[r];
    const float* hr = hs + i * FD + lane;
    float* dst = hpb + r * FD + lane;
    dst[0] = hr[0]; dst[64] = hr[64]; dst[128] = hr[128]; dst[192] = hr[192];
    int j2 = (lane < NN1) ? sel[lane] : 0;
    bool bit = (lane < NN1) && ((abits[i * 4 + (j2 >> 5)] >> (j2 & 31)) & 1);
    unsigned long long m = __ballot(bit);
    if (lane == 0) adjp[(size_t)bl * NN1 + r] = m;
  }
  __syncthreads();
  float* zb = zbuf + (size_t)bl * 8192;
  if (tid < FD) {
    float mx = -3.402823466e38f, sm2 = 0.0f;
    for (int r = 0; r < NN1; ++r) {
      float v = hs[sel[r] * FD + tid];
      mx = fmaxf(mx, v); sm2 += v;
    }
    zb[7168 + tid] = mx;
    zb[7424 + tid] = sm2 / 56.0f;
  }
}

// ---------------------------------------------------------------------------
// K3: stage-2 conv (56 nodes, K=256); same wide-prop structure. LDS 87,488 B.
// ---------------------------------------------------------------------------
__global__ __launch_bounds__(512) void k_stage2(
    const float* __restrict__ hp1, const unsigned long long* __restrict__ adjp,
    const float* __restrict__ wg, const float* __restrict__ wsp,
    float* __restrict__ h2)
{
  extern __shared__ float sm[];
  float* hs   = sm;                                // 56*256 = 14336
  float* bufw = hs + NN1 * FD;                     // 57*128 = 7296 (row 56 = 0)
  unsigned long long* rowm = (unsigned long long*)(bufw + 7296); // 56 u64
  float* dis0 = (float*)(rowm + 56);               // 64
  float* dis1 = dis0 + 64;                         // 64

  const int tid = threadIdx.x, lane = tid & 63, wv = tid >> 6;
  const int bl = blockIdx.x;
  const float* hb = hp1 + (size_t)bl * (NN1 * FD);
  for (int q = tid; q < NN1 * 64; q += 512)
    ((float4*)hs)[q] = ((const float4*)hb)[q];
  if (tid < 128) bufw[56 * 128 + tid] = 0.0f;
  if (tid < NN1) {
    unsigned long long m = adjp[(size_t)bl * NN1 + tid];
    rowm[tid] = m;
    int d = __popcll(m);
    dis0[tid] = (d > 0) ? (1.0f / sqrtf((float)d)) : 0.0f;
    dis1[tid] = 1.0f / sqrtf((float)(d + 1));
  }
  __syncthreads();

  auto nsum2 = [&](int i) {
    unsigned long long m = rowm[i];
    unsigned lo = (unsigned)__builtin_amdgcn_readfirstlane((unsigned)m);
    unsigned hi = (unsigned)__builtin_amdgcn_readfirstlane((unsigned)(m >> 32));
    unsigned long long u = ((unsigned long long)hi << 32) | (unsigned long long)lo;
    float2 s0 = {0,0}, s1 = {0,0}, s2 = {0,0}, s3 = {0,0};
    while (u) {
      int j0 = (int)__builtin_ctzll(u); u &= u - 1;
      int j1 = u ? (int)__builtin_ctzll(u) : 56; u &= u - 1;
      int j2 = u ? (int)__builtin_ctzll(u) : 56; u &= u - 1;
      int j3 = u ? (int)__builtin_ctzll(u) : 56; u &= u - 1;
      float2 p0 = *(const float2*)&bufw[j0 * 128 + 2 * lane];
      float2 p1 = *(const float2*)&bufw[j1 * 128 + 2 * lane];
      float2 p2 = *(const float2*)&bufw[j2 * 128 + 2 * lane];
      float2 p3 = *(const float2*)&bufw[j3 * 128 + 2 * lane];
      s0.x += p0.x; s0.y += p0.y; s1.x += p1.x; s1.y += p1.y;
      s2.x += p2.x; s2.y += p2.y; s3.x += p3.x; s3.y += p3.y;
    }
    return make_float2((s0.x + s1.x) + (s2.x + s3.x),
                       (s0.y + s1.y) + (s2.y + s3.y));
  };

  float* h2b = h2 + (size_t)bl * (NN1 * FD);

  float a2r[2][7], a1r[2][7], a0r[2][7];
#pragma unroll
  for (int s = 0; s < 2; ++s) {
    float aG[7], q2[7], q1[7], q0[7];
#pragma unroll
    for (int t = 0; t < 7; ++t) { aG[t] = 0.f; q2[t] = 0.f; q1[t] = 0.f; q0[t] = 0.f; }
    const float* pG = wg  + 2 * lane + s;
    const float* p2 = wsp + 2 * (FD * HD) + 2 * lane + s;
    const float* p1 = wsp + 1 * (FD * HD) + 2 * lane + s;
    const float* p0 = wsp + 2 * lane + s;
    for (int kq = 0; kq < 64; ++kq) {
      int k0 = kq * 4;
      float g0 = pG[(k0+0)*HD], g1 = pG[(k0+1)*HD], g2 = pG[(k0+2)*HD], g3 = pG[(k0+3)*HD];
      float s0 = p2[(k0+0)*HD], s1 = p2[(k0+1)*HD], s2 = p2[(k0+2)*HD], s3 = p2[(k0+3)*HD];
      float u0 = p1[(k0+0)*HD], u1 = p1[(k0+1)*HD], u2 = p1[(k0+2)*HD], u3 = p1[(k0+3)*HD];
      float v0 = p0[(k0+0)*HD], v1 = p0[(k0+1)*HD], v2 = p0[(k0+2)*HD], v3 = p0[(k0+3)*HD];
#pragma unroll
      for (int t = 0; t < 7; ++t) {
        int r = wv + 8 * t;
        float4 xq = *(const float4*)(hs + r * FD + k0);
        aG[t] += xq.x*g0 + xq.y*g1 + xq.z*g2 + xq.w*g3;
        q2[t] += xq.x*s0 + xq.y*s1 + xq.z*s2 + xq.w*s3;
        q1[t] += xq.x*u0 + xq.y*u1 + xq.z*u2 + xq.w*u3;
        q0[t] += xq.x*v0 + xq.y*v1 + xq.z*v2 + xq.w*v3;
      }
    }
#pragma unroll
    for (int t = 0; t < 7; ++t) {
      int r = wv + 8 * t;
      bufw[r * 128 + 2 * lane + s] = dis1[r] * aG[t];
      a2r[s][t] = q2[t]; a1r[s][t] = q1[t]; a0r[s][t] = q0[t];
    }
  }
  __syncthreads();
  // GCN prop
#pragma unroll
  for (int t = 0; t < 7; ++t) {
    int i = wv + 8 * t;
    float2 self = *(const float2*)&bufw[i * 128 + 2 * lane];
    float2 ns = nsum2(i);
    float d1 = dis1[i];
    float2 o = make_float2(fmaxf(d1 * (self.x + ns.x), 0.f),
                           fmaxf(d1 * (self.y + ns.y), 0.f));
    *(float2*)&h2b[i * FD + 2 * lane] = o;
  }
  __syncthreads();
#pragma unroll
  for (int t = 0; t < 7; ++t) {
    int r = wv + 8 * t;
    float d0r = dis0[r];
    *(float2*)&bufw[r * 128 + 2 * lane] = make_float2(d0r * a2r[0][t], d0r * a2r[1][t]);
  }
  __syncthreads();
  float2 ur[7], cacc[7];
#pragma unroll
  for (int t = 0; t < 7; ++t) {
    int i = wv + 8 * t;
    float2 ns = nsum2(i);
    float sc0 = -dis0[i] * dis0[i];
    ur[t] = make_float2(sc0 * ns.x, sc0 * ns.y);
    cacc[t] = make_float2(-a2r[0][t], -a2r[1][t]);
  }
  __syncthreads();
#pragma unroll
  for (int t = 0; t < 7; ++t) {
    int r = wv + 8 * t;
    *(float2*)&bufw[r * 128 + 2 * lane] = ur[t];
  }
  __syncthreads();
#pragma unroll
  for (int t = 0; t < 7; ++t) {
    int i = wv + 8 * t;
    float2 ns = nsum2(i);
    float d0i = dis0[i];
    cacc[t].x -= 2.0f * d0i * ns.x;
    cacc[t].y -= 2.0f * d0i * ns.y;
  }
  __syncthreads();
#pragma unroll
  for (int t = 0; t < 7; ++t) {
    int r = wv + 8 * t;
    float d0r = dis0[r];
    *(float2*)&bufw[r * 128 + 2 * lane] = make_float2(d0r * a1r[0][t], d0r * a1r[1][t]);
  }
  __syncthreads();
#pragma unroll
  for (int t = 0; t < 7; ++t) {
    int i = wv + 8 * t;
    float2 ns = nsum2(i);
    float d0i = dis0[i];
    float2 o = make_float2(fmaxf(cacc[t].x - d0i * ns.x + a0r[0][t], 0.f),
                           fmaxf(cacc[t].y - d0i * ns.y + a0r[1][t], 0.f));
    *(float2*)&h2b[i * FD + HD + 2 * lane] = o;
  }
}

// ---------------------------------------------------------------------------
// K4: pool2 + readout; flat h -> zbuf[0..7167], x2 -> zbuf[7680..]
// ---------------------------------------------------------------------------
__global__ __launch_bounds__(256) void k_pool2(
    const float* __restrict__ h2, const unsigned long long* __restrict__ adjp,
    float* __restrict__ zbuf)
{
  extern __shared__ float smemf[];
  float* hs = smemf;                                        // 56*256
  unsigned long long* rowm = (unsigned long long*)(hs + NN1 * FD);
  float* dinv = (float*)(rowm + 56);
  float* sc = dinv + 64;
  int* sel = (int*)(sc + 64);

  const int tid = threadIdx.x, lane = tid & 63, wv = tid >> 6;
  const int bl = blockIdx.x;
  const float* hb = h2 + (size_t)bl * (NN1 * FD);
  for (int q = tid; q < NN1 * 64; q += 256)
    ((float4*)hs)[q] = ((const float4*)hb)[q];
  if (tid < NN1) {
    unsigned long long m = adjp[(size_t)bl * NN1 + tid];
    rowm[tid] = m;
    int d = __popcll(m);
    dinv[tid] = (d > 0) ? (1.0f / (float)d) : 0.0f;
  }
  __syncthreads();
  for (int i = wv; i < NN1; i += 4) {
    float nb0 = 0, nb1 = 0, nb2 = 0, nb3 = 0;
    unsigned long long m = rowm[i];
    unsigned ulo = (unsigned)__builtin_amdgcn_readfirstlane((unsigned)m);
    unsigned uhi = (unsigned)__builtin_amdgcn_readfirstlane((unsigned)(m >> 32));
    while (ulo) {
      int j = __builtin_ctz(ulo); ulo &= ulo - 1;
      const float* hr = hs + j * FD + lane;
      nb0 += hr[0]; nb1 += hr[64]; nb2 += hr[128]; nb3 += hr[192];
    }
    while (uhi) {
      int j = 32 + __builtin_ctz(uhi); uhi &= uhi - 1;
      const float* hr = hs + j * FD + lane;
      nb0 += hr[0]; nb1 += hr[64]; nb2 += hr[128]; nb3 += hr[192];
    }
    const float* hi = hs + i * FD + lane;
    float di = dinv[i];
    float s = fabsf(hi[0] - di * nb0) + fabsf(hi[64] - di * nb1)
            + fabsf(hi[128] - di * nb2) + fabsf(hi[192] - di * nb3);
    for (int off = 32; off; off >>= 1) s += __shfl_xor(s, off);
    if (lane == 0) sc[i] = s;
  }
  __syncthreads();
  if (tid < NN1) {
    float my = sc[tid];
    int cnt = 0;
    for (int j = 0; j < NN1; ++j) {
      float sj = sc[j];
      cnt += (sj > my) || (sj == my && j < tid);
    }
    if (cnt < NN2) sel[cnt] = tid;
  }
  __syncthreads();
  float* zb = zbuf + (size_t)bl * 8192;
  for (int r = wv; r < NN2; r += 4) {
    const float* hr = hs + sel[r] * FD + lane;
    float* dst = zb + r * FD + lane;
    dst[0] = hr[0]; dst[64] = hr[64]; dst[128] = hr[128]; dst[192] = hr[192];
  }
  {
    float mx = -3.402823466e38f, sm2 = 0.0f;
    for (int r = 0; r < NN2; ++r) {
      float v = hs[sel[r] * FD + tid];
      mx = fmaxf(mx, v); sm2 += v;
    }
    zb[7680 + tid] = mx;
    zb[7936 + tid] = sm2 / 28.0f;
  }
}

// ---------------------------------------------------------------------------
// K5: fused lin1. Block = 8 graphs x full K x all 256 cols. 512 thr.
// ---------------------------------------------------------------------------
__global__ __launch_bounds__(512) void k_lin1f(
    const float* __restrict__ zbuf, const float* __restrict__ w,
    const float* __restrict__ bias, float* __restrict__ fbuf)
{
  __shared__ float smem[8576];           // wt: 32*260=8320 | zt: 32*8=256
  float* wt = smem;
  float* zt = smem + 8320;

  const int tid = threadIdx.x;
  const int col = tid & 63;
  const int ksub = tid >> 6;             // 0..7
  const int g0 = blockIdx.x * 8;
  const int gz = tid >> 5, kz = tid & 31;  // z staging (tid<256)

  float acc[8][4];
#pragma unroll
  for (int g = 0; g < 8; ++g)
#pragma unroll
    for (int c = 0; c < 4; ++c) acc[g][c] = 0.f;

  const float* wbase = w + (size_t)ksub * 256 + col * 4;
  const float* zbase = zbuf + (size_t)(g0 + gz) * 8192 + kz;

  float4 wr4[4]; float zr1 = 0.f;
#pragma unroll
  for (int q = 0; q < 4; ++q)
    wr4[q] = *(const float4*)(wbase + (size_t)(8 * q) * 256);
  if (tid < 256) zr1 = zbase[0];
#pragma unroll
  for (int q = 0; q < 4; ++q)
    *(float4*)&wt[(ksub + 8 * q) * 260 + col * 4] = wr4[q];
  if (tid < 256) zt[kz * 8 + gz] = zr1;
  __syncthreads();

  for (int it = 0; it < 256; ++it) {
    if (it + 1 < 256) {
      const float* wn = wbase + (size_t)(it + 1) * 32 * 256;
#pragma unroll
      for (int q = 0; q < 4; ++q)
        wr4[q] = *(const float4*)(wn + (size_t)(8 * q) * 256);
      if (tid < 256) zr1 = zbase[(it + 1) * 32];
    }
#pragma unroll
    for (int kk = 0; kk < 4; ++kk) {
      int k = ksub * 4 + kk;
      float4 za = *(const float4*)&zt[k * 8];
      float4 zb = *(const float4*)&zt[k * 8 + 4];
      float4 wv = *(const float4*)&wt[k * 260 + col * 4];
      acc[0][0] += za.x * wv.x; acc[0][1] += za.x * wv.y; acc[0][2] += za.x * wv.z; acc[0][3] += za.x * wv.w;
      acc[1][0] += za.y * wv.x; acc[1][1] += za.y * wv.y; acc[1][2] += za.y * wv.z; acc[1][3] += za.y * wv.w;
      acc[2][0] += za.z * wv.x; acc[2][1] += za.z * wv.y; acc[2][2] += za.z * wv.z; acc[2][3] += za.z * wv.w;
      acc[3][0] += za.w * wv.x; acc[3][1] += za.w * wv.y; acc[3][2] += za.w * wv.z; acc[3][3] += za.w * wv.w;
      acc[4][0] += zb.x * wv.x; acc[4][1] += zb.x * wv.y; acc[4][2] += zb.x * wv.z; acc[4][3] += zb.x * wv.w;
      acc[5][0] += zb.y * wv.x; acc[5][1] += zb.y * wv.y; acc[5][2] += zb.y * wv.z; acc[5][3] += zb.y * wv.w;
      acc[6][0] += zb.z * wv.x; acc[6][1] += zb.z * wv.y; acc[6][2] += zb.z * wv.z; acc[6][3] += zb.z * wv.w;
      acc[7][0] += zb.w * wv.x; acc[7][1] += zb.w * wv.y; acc[7][2] += zb.w * wv.z; acc[7][3] += zb.w * wv.w;
    }
    __syncthreads();
    if (it + 1 < 256) {
#pragma unroll
      for (int q = 0; q < 4; ++q)
        *(float4*)&wt[(ksub + 8 * q) * 260 + col * 4] = wr4[q];
      if (tid < 256) zt[kz * 8 + gz] = zr1;
      __syncthreads();
    }
  }

  // reduce 8 ksub partials (tree via LDS)
  float* red = smem;
  for (int half = 4; half >= 1; half >>= 1) {
    if (ksub >= half && ksub < 2 * half) {
      float* dst = red + ((ksub - half) * 64 + col) * 33;
#pragma unroll
      for (int g = 0; g < 8; ++g)
#pragma unroll
        for (int c = 0; c < 4; ++c) dst[g * 4 + c] = acc[g][c];
    }
    __syncthreads();
    if (ksub < half) {
      const float* src = red + (ksub * 64 + col) * 33;
#pragma unroll
      for (int g = 0; g < 8; ++g)
#pragma unroll
        for (int c = 0; c < 4; ++c) acc[g][c] += src[g * 4 + c];
    }
    __syncthreads();
  }
  if (ksub == 0) {
    float4 bv = *(const float4*)(bias + col * 4);
#pragma unroll
    for (int g = 0; g < 8; ++g) {
      float4 o;
      o.x = fmaxf(acc[g][0] + bv.x, 0.f);
      o.y = fmaxf(acc[g][1] + bv.y, 0.f);
      o.z = fmaxf(acc[g][2] + bv.z, 0.f);
      o.w = fmaxf(acc[g][3] + bv.w, 0.f);
      *(float4*)&fbuf[(size_t)(g0 + g) * 256 + col * 4] = o;
    }
  }
}

// ---------------------------------------------------------------------------
// K6: features = relu(f @ lin2_w + b2); x_lo = softmax(features)
// ---------------------------------------------------------------------------
__global__ __launch_bounds__(128) void k_head(
    const float* __restrict__ fbuf, const float* __restrict__ w2,
    const float* __restrict__ b2, float* __restrict__ out, int b0)
{
  __shared__ __align__(16) float fs[256];
  __shared__ float red[2];
  const int tid = threadIdx.x, lane = tid & 63, wv = tid >> 6;
  const int bl = blockIdx.x, b = b0 + bl;
  for (int i = tid; i < 256; i += 128) fs[i] = fbuf[(size_t)bl * 256 + i];
  __syncthreads();
  float acc = b2[tid];
  for (int k = 0; k < 256; k += 4) {
    float4 fq = *(const float4*)(fs + k);
    acc += fq.x * w2[(k + 0) * 128 + tid] + fq.y * w2[(k + 1) * 128 + tid]
         + fq.z * w2[(k + 2) * 128 + tid] + fq.w * w2[(k + 3) * 128 + tid];
  }
  float feat = fmaxf(acc, 0.0f);
  out[(size_t)(NB * 128) + (size_t)b * 128 + tid] = feat;
  float m = feat;
  for (int off = 32; off; off >>= 1) m = fmaxf(m, __shfl_xor(m, off));
  if (lane == 0) red[wv] = m;
  __syncthreads();
  m = fmaxf(red[0], red[1]);
  float e = expf(feat - m);
  float s = e;
  for (int off = 32; off; off >>= 1) s += __shfl_xor(s, off);
  __syncthreads();
  if (lane == 0) red[wv] = s;
  __syncthreads();
  s = red[0] + red[1];
  out[(size_t)b * 128 + tid] = e / s;
}

// ---------------------------------------------------------------------------
extern "C" void kernel_launch(void* const* d_in, const int* in_sizes, int n_in,
                              void* d_out, int out_size, void* d_ws, size_t ws_size,
                              hipStream_t stream) {
  const float* x    = (const float*)d_in[0];
  const float* adj  = (const float*)d_in[1];
  const float* wg1  = (const float*)d_in[2];
  const float* wsp1 = (const float*)d_in[3];
  const float* wg2  = (const float*)d_in[4];
  const float* wsp2 = (const float*)d_in[5];
  const float* l1w  = (const float*)d_in[6];
  const float* l1b  = (const float*)d_in[7];
  const float* l2w  = (const float*)d_in[8];
  const float* l2b  = (const float*)d_in[9];
  float* out = (float*)d_out;

  auto al = [](size_t v) { return (v + 255) & ~(size_t)255; };
  size_t oh1, ohp1, oadjp, oz, of;
  auto plan = [&](int g) -> size_t {
    size_t o = 0;
    oh1 = o;   o += al((size_t)g * NN0 * FD * 4);   // h1 (h2 overlay)
    ohp1 = o;  o += al((size_t)g * NN1 * FD * 4);
    oadjp = o; o += al((size_t)g * NN1 * 8);
    oz = o;    o += al((size_t)g * 8192 * 4);
    of = o;    o += al((size_t)g * FD * 4);
    return o;
  };
  int G = 2048;
  while (G > 64 && plan(G) > ws_size) G >>= 1;
  if (plan(G) > ws_size) return;

  char* wsb = (char*)d_ws;
  float* h1  = (float*)(wsb + oh1);
  float* hp1 = (float*)(wsb + ohp1);
  unsigned long long* adjp = (unsigned long long*)(wsb + oadjp);
  float* zbuf = (float*)(wsb + oz);
  float* fbuf = (float*)(wsb + of);

  const size_t LDS1 = (size_t)(12432 + 14336 + 448 + 112 + 112) * 4;  // 109,760
  const size_t LDS2 = (size_t)(NN0*FD + 448 + 112 + 112 + 56) * 4;    // 116,576
  const size_t LDS3 = (size_t)(NN1*FD + 7296 + 112 + 64 + 64) * 4;    // 87,488
  const size_t LDS4 = (size_t)(NN1*FD + 112 + 64 + 64 + 32) * 4;      // 58,432

  for (int b0 = 0; b0 < NB; b0 += G) {
    k_stage1<<<G, 512, LDS1, stream>>>(x, adj, wg1, wsp1, h1, b0);
    k_pool1<<<G, 512, LDS2, stream>>>(h1, adj, hp1, adjp, zbuf, b0);
    k_stage2<<<G, 512, LDS3, stream>>>(hp1, adjp, wg2, wsp2, h1);
    k_pool2<<<G, 256, LDS4, stream>>>(h1, adjp, zbuf);
    k_lin1f<<<G / 8, 512, 0, stream>>>(zbuf, l1w, l1b, fbuf);
    k_head<<<G, 128, 0, stream>>>(fbuf, l2w, l2b, out, b0);
  }
}